// Round 8
// baseline (1788.745 us; speedup 1.0000x reference)
//
#include <hip/hip_runtime.h>
#include <stdint.h>

typedef __bf16 bf16_t;
typedef __bf16 bf16x8 __attribute__((ext_vector_type(8)));
typedef __bf16 bf16x4 __attribute__((ext_vector_type(4)));
typedef __bf16 bf16x2 __attribute__((ext_vector_type(2)));
typedef float f32x4 __attribute__((ext_vector_type(4)));

#define SCALE 0.17677669529663687f

__device__ __forceinline__ f32x4 mfma16(bf16x8 a, bf16x8 b, f32x4 c) {
  return __builtin_amdgcn_mfma_f32_16x16x32_bf16(a, b, c, 0, 0, 0);
}

// XOR-swizzled LDS byte offset: 16B-granule index XORed with (row&7).
__device__ __forceinline__ int swz(int row, int colByte, int strideB) {
  return row * strideB + ((((colByte >> 4) ^ (row & 7)) << 4) | (colByte & 15));
}

// lgkm-only barrier: orders LDS producer->consumer, leaves global/DMA loads
// in flight (no vmcnt drain). Proven r5-r7.
__device__ __forceinline__ void barrier_nd() {
  asm volatile("s_waitcnt lgkmcnt(0)" ::: "memory");
  __builtin_amdgcn_s_barrier();
  asm volatile("" ::: "memory");
}
// Full barrier: waits own DMA/global loads (vmcnt) + LDS, then barrier.
// After this, every wave's global_load_lds results are visible to all.
__device__ __forceinline__ void barrier_vm() {
  asm volatile("s_waitcnt vmcnt(0) lgkmcnt(0)" ::: "memory");
  __builtin_amdgcn_s_barrier();
  asm volatile("" ::: "memory");
}

// async global->LDS, 16B per lane. LDS dest = wave-uniform base + lane*16.
__device__ __forceinline__ void dma16(const float* g, char* lds) {
  __builtin_amdgcn_global_load_lds(
      (const __attribute__((address_space(1))) uint32_t*)(uintptr_t)g,
      (__attribute__((address_space(3))) uint32_t*)(uint32_t)(uintptr_t)lds,
      16, 0, 0);
}

union CvtU { bf16x2 h; unsigned int u; };
union PaU { unsigned int u[4]; bf16x8 v; };

// ws: bf16 weights. q_wb [0,36864) PRE-SCALED by SCALE, kv_wb [36864,110592),
// proj_wb [110592,147456). 294912 bytes.
__global__ void prep(const float* __restrict__ qw, const float* __restrict__ kvw,
                     const float* __restrict__ pw, bf16_t* __restrict__ wsb) {
  int i = blockIdx.x * 256 + threadIdx.x;
#pragma unroll
  for (int j = 0; j < 4; ++j) {
    int e = i * 4 + j;
    float v;
    if (e < 36864) v = qw[e] * SCALE;
    else if (e < 110592) v = kvw[e - 36864];
    else v = pw[e - 110592];
    wsb[e] = (bf16_t)v;
  }
}

template <bool WS>
__device__ __forceinline__ bf16x8 ldw(const bf16_t* __restrict__ wb,
                                      const float* __restrict__ wf, int off) {
  if constexpr (WS) {
    return *(const bf16x8*)(wb + off);
  } else {
    const float4* p = (const float4*)(wf + off);
    float4 a = p[0], c = p[1];
    bf16x8 r;
    r[0] = (bf16_t)a.x; r[1] = (bf16_t)a.y; r[2] = (bf16_t)a.z; r[3] = (bf16_t)a.w;
    r[4] = (bf16_t)c.x; r[5] = (bf16_t)c.y; r[6] = (bf16_t)c.z; r[7] = (bf16_t)c.w;
    return r;
  }
}

// Persistent: 256 blocks (1/CU) x 32 windows, 512 threads = 8 waves.
// LDS 120 KB:
//   RA @     0 : [64][384B] x2-bf16 -> Q -> att-out (swizzled)
//   RK @ 24576 : [64][384B] K (swizzled)
//   RV @ 49152 : [192][128B] V^T (swizzled)
//   PF @ 73728 : 48 KB f32 DMA buffer, time-shared x2(j) then x1(j)
// Per window: {vmcnt+bar} convert {bar} +x1DMA phaseA {vmcnt+bar} phaseB
// {bar} +x2DMA(j+1) attn {bar} outproj. No VGPR state crosses a barrier;
// all HBM input latency hidden under compute via DMA.
template <bool WS>
__global__ __launch_bounds__(512, 2) void wca_main(
    const float* __restrict__ x1, const float* __restrict__ x2,
    const float* __restrict__ mask,
    const float* __restrict__ qw_f, const float* __restrict__ qb,
    const float* __restrict__ kvw_f, const float* __restrict__ kvb,
    const float* __restrict__ pw_f, const float* __restrict__ pb,
    const float* __restrict__ table,
    const bf16_t* __restrict__ wsb,
    float* __restrict__ out) {
  extern __shared__ char smem[];
  char* RA = smem;
  char* RK = smem + 24576;
  char* RV = smem + 49152;
  char* PF = smem + 73728;

  const int t = threadIdx.x;
  const int w = t >> 6, l = t & 63, lo = l & 15, hi = l >> 4;
  const int bid = blockIdx.x;
  const int rtB = w & 3, cgB = w >> 2;

  const bf16_t* q_wb = wsb;
  const bf16_t* kv_wb = wsb + 36864;
  const bf16_t* p_wb = wsb + 110592;

  // prologue: DMA x2(window bid) -> PF, linear
  {
    const float* x2w = x2 + (size_t)bid * 12288;
#pragma unroll
    for (int k = 0; k < 6; ++k)
      dma16(x2w + ((w * 6 + k) * 64 + l) * 4, PF + (w * 6 + k) * 1024);
  }

#pragma unroll 1
  for (int j = 0; j < 32; ++j) {
    const int win = j * 256 + bid;

    // ---------- (1) PF = x2(j) ready ----------
    barrier_vm();

    // ---------- (2) convert PF(x2 f32, linear) -> RA (bf16, swz) ----------
#pragma unroll
    for (int it = 0; it < 6; ++it) {
      int G = it * 512 + t;              // 16B granule, [0,3072)
      f32x4 v = *(const f32x4*)(PF + G * 16);
      bf16x4 o;
      o[0] = (bf16_t)v[0]; o[1] = (bf16_t)v[1];
      o[2] = (bf16_t)v[2]; o[3] = (bf16_t)v[3];
      int n = G / 48, cb = (G - n * 48) * 8;
      *(bf16x4*)(RA + swz(n, cb, 384)) = o;
    }
    barrier_nd();  // (3) RA ready; PF dead

    // ---------- (4) issue x1(j) DMA -> PF, swizzled source ----------
    // physical granule P=(row,c) receives logical granule (row, c^(row&7));
    // readers fetch logical c0 at physical c0^(row&7).
    {
      const float* x1w = x1 + (size_t)win * 12288;
#pragma unroll
      for (int k = 0; k < 6; ++k) {
        int P = (w * 6 + k) * 64 + l;
        int row = P / 48, c = P - row * 48;
        int Lg = row * 48 + (c ^ (row & 7));
        dma16(x1w + Lg * 4, PF + P * 16);
      }
    }

    // ---------- (5) phase A: KV proj from RA ----------
    // wave w: K cols w*48.. (w<4) | V cols (w-4)*48.. (w>=4)
    {
      bf16x8 wA[6][3];
#pragma unroll
      for (int kk = 0; kk < 6; ++kk)
#pragma unroll
        for (int ct = 0; ct < 3; ++ct) {
          int row = w * 48 + ct * 16 + lo;
          wA[kk][ct] = ldw<WS>(kv_wb, kvw_f, row * 192 + kk * 32 + hi * 8);
        }
      f32x4 acc[4][3];
#pragma unroll
      for (int rt = 0; rt < 4; ++rt)
#pragma unroll
        for (int ct = 0; ct < 3; ++ct) { f32x4 z = {0.f, 0.f, 0.f, 0.f}; acc[rt][ct] = z; }
#pragma unroll
      for (int kk = 0; kk < 6; ++kk) {
        bf16x8 a[4];
#pragma unroll
        for (int rt = 0; rt < 4; ++rt)
          a[rt] = *(const bf16x8*)(RA + swz(rt * 16 + lo, (kk * 4 + hi) * 16, 384));
#pragma unroll
        for (int rt = 0; rt < 4; ++rt)
#pragma unroll
          for (int ct = 0; ct < 3; ++ct)
            acc[rt][ct] = mfma16(a[rt], wA[kk][ct], acc[rt][ct]);
      }
      if (w < 4) {
#pragma unroll
        for (int ct = 0; ct < 3; ++ct) {
          int och = w * 48 + ct * 16 + lo;
          float bv = kvb[och];
#pragma unroll
          for (int rt = 0; rt < 4; ++rt)
#pragma unroll
            for (int i = 0; i < 4; ++i)
              *(bf16_t*)(RK + swz(rt * 16 + hi * 4 + i, och * 2, 384)) =
                  (bf16_t)(acc[rt][ct][i] + bv);
        }
      } else {
#pragma unroll
        for (int ct = 0; ct < 3; ++ct) {
          int och = (w - 4) * 48 + ct * 16 + lo;
          float bv = kvb[192 + och];
#pragma unroll
          for (int rt = 0; rt < 4; ++rt) {
            int n0 = rt * 16 + hi * 4;
            bf16x4 pk;
#pragma unroll
            for (int i = 0; i < 4; ++i) pk[i] = (bf16_t)(acc[rt][ct][i] + bv);
            *(bf16x4*)(RV + swz(och, n0 * 2, 128)) = pk;
          }
        }
      }
    }
    // ---------- (6) PF = x1(j) ready; RK/RV ready; RA(x2) dead ----------
    barrier_vm();

    // ---------- (7) phase B: Q proj from PF(x1) -> RA ----------
    {
      const int arow = rtB * 16 + lo;
      const int xr = arow & 7;
      const char* PFrow = PF + arow * 768;
      f32x4 acc[6];
#pragma unroll
      for (int ct = 0; ct < 6; ++ct) { f32x4 z = {0.f, 0.f, 0.f, 0.f}; acc[ct] = z; }
#pragma unroll
      for (int kh = 0; kh < 2; ++kh) {
        bf16x8 wB[3][6];
#pragma unroll
        for (int k2 = 0; k2 < 3; ++k2)
#pragma unroll
          for (int ct = 0; ct < 6; ++ct) {
            int col = cgB * 96 + ct * 16 + lo;
            wB[k2][ct] = ldw<WS>(q_wb, qw_f, col * 192 + (kh * 3 + k2) * 32 + hi * 8);
          }
#pragma unroll
        for (int k2 = 0; k2 < 3; ++k2) {
          int c0 = (kh * 3 + k2) * 8 + hi * 2;
          int p0 = c0 ^ xr;
          f32x4 va = *(const f32x4*)(PFrow + p0 * 16);
          f32x4 vb = *(const f32x4*)(PFrow + (p0 ^ 1) * 16);
          bf16x8 a;
          a[0] = (bf16_t)va[0]; a[1] = (bf16_t)va[1];
          a[2] = (bf16_t)va[2]; a[3] = (bf16_t)va[3];
          a[4] = (bf16_t)vb[0]; a[5] = (bf16_t)vb[1];
          a[6] = (bf16_t)vb[2]; a[7] = (bf16_t)vb[3];
#pragma unroll
          for (int ct = 0; ct < 6; ++ct) acc[ct] = mfma16(a, wB[k2][ct], acc[ct]);
        }
      }
#pragma unroll
      for (int ct = 0; ct < 6; ++ct) {
        int col = cgB * 96 + ct * 16 + lo;
#pragma unroll
        for (int i = 0; i < 4; ++i) {
          float val = WS ? (acc[ct][i] + qb[col] * SCALE)
                         : (acc[ct][i] + qb[col]) * SCALE;
          *(bf16_t*)(RA + swz(rtB * 16 + hi * 4 + i, col * 2, 384)) = (bf16_t)val;
        }
      }
    }
    barrier_nd();  // (8) Q ready; PF(x1) dead

    // ---------- (9) issue x2(j+1) DMA -> PF, linear ----------
    if (j < 31) {
      const float* x2w = x2 + (size_t)(win + 256) * 12288;
#pragma unroll
      for (int k = 0; k < 6; ++k)
        dma16(x2w + ((w * 6 + k) * 64 + l) * 4, PF + (w * 6 + k) * 1024);
    }

    // ---------- (10) attention: wave = (rt3 = w>>1, hh = w&1) ----------
    {
      const int rt3 = w >> 1, hh = w & 1, rbase = rt3 * 16;
      const int r = rbase + lo;
      const float* maskp = mask + (size_t)(win & 1023) * 4096 + r * 64;
      f32x4 mk[4];
      int ridx[4][4];
#pragma unroll
      for (int ct = 0; ct < 4; ++ct) {
        mk[ct] = *(const f32x4*)(maskp + ct * 16 + hi * 4);
#pragma unroll
        for (int i = 0; i < 4; ++i) {
          int c = ct * 16 + hi * 4 + i;
          ridx[ct][i] = (((r >> 3) - (c >> 3) + 7) * 15 + ((r & 7) - (c & 7) + 7)) * 6;
        }
      }
#pragma unroll
      for (int hq = 0; hq < 3; ++hq) {
        const int h = hh * 3 + hq;
        f32x4 cb[4];
#pragma unroll
        for (int ct = 0; ct < 4; ++ct) {
#pragma unroll
          for (int i = 0; i < 4; ++i) cb[ct][i] = table[ridx[ct][i] + h];
          cb[ct] += mk[ct];
        }
        bf16x8 qa = *(const bf16x8*)(RA + swz(r, h * 64 + hi * 16, 384));
        f32x4 s[4];
#pragma unroll
        for (int ct = 0; ct < 4; ++ct) {
          bf16x8 ka = *(const bf16x8*)(RK + swz(ct * 16 + lo, h * 64 + hi * 16, 384));
          s[ct] = mfma16(ka, qa, cb[ct]);  // lane holds S[r][ct*16+hi*4+i]
        }
        float mx = -1e30f;
#pragma unroll
        for (int ct = 0; ct < 4; ++ct)
#pragma unroll
          for (int i = 0; i < 4; ++i) mx = fmaxf(mx, s[ct][i]);
        mx = fmaxf(mx, __shfl_xor(mx, 16));
        mx = fmaxf(mx, __shfl_xor(mx, 32));
        float sum = 0.f;
#pragma unroll
        for (int ct = 0; ct < 4; ++ct)
#pragma unroll
          for (int i = 0; i < 4; ++i) {
            float p = __expf(s[ct][i] - mx);
            s[ct][i] = p;
            sum += p;
          }
        sum += __shfl_xor(sum, 16);
        sum += __shfl_xor(sum, 32);
        float rinv = 1.0f / sum;
        unsigned int word[4][2];
#pragma unroll
        for (int ct = 0; ct < 4; ++ct)
#pragma unroll
          for (int i2 = 0; i2 < 2; ++i2) {
            CvtU cu;
            cu.h[0] = (bf16_t)(s[ct][2 * i2] * rinv);
            cu.h[1] = (bf16_t)(s[ct][2 * i2 + 1] * rinv);
            word[ct][i2] = cu.u;
          }
        f32x4 o0 = {0.f, 0.f, 0.f, 0.f}, o1 = {0.f, 0.f, 0.f, 0.f};
#pragma unroll
        for (int k2 = 0; k2 < 2; ++k2) {
          PaU pa;
#pragma unroll
          for (int j2 = 0; j2 < 4; ++j2) {
            int src = lo + ((hi & 1) << 5) + ((j2 >> 1) << 4);
            unsigned int wa = (unsigned int)__shfl((int)word[2 * k2][j2 & 1], src);
            unsigned int wb = (unsigned int)__shfl((int)word[2 * k2 + 1][j2 & 1], src);
            pa.u[j2] = (hi & 2) ? wb : wa;
          }
          bf16x8 v0 = *(const bf16x8*)(RV + swz(h * 32 + lo, k2 * 64 + hi * 16, 128));
          bf16x8 v1 = *(const bf16x8*)(RV + swz(h * 32 + 16 + lo, k2 * 64 + hi * 16, 128));
          o0 = mfma16(pa.v, v0, o0);
          o1 = mfma16(pa.v, v1, o1);
        }
        // att-out overwrites this wave's own (rows x head-cols) of RA
#pragma unroll
        for (int i = 0; i < 4; ++i) {
          int rr = rbase + hi * 4 + i;
          *(bf16_t*)(RA + swz(rr, h * 64 + lo * 2, 384)) = (bf16_t)o0[i];
          *(bf16_t*)(RA + swz(rr, h * 64 + 32 + lo * 2, 384)) = (bf16_t)o1[i];
        }
      }
    }
    barrier_nd();  // (11) att-out fully in RA

    // ---------- (12) out proj: rows rtB*16, cols cgB*96 ----------
    {
      f32x4 acc[6];
#pragma unroll
      for (int ct = 0; ct < 6; ++ct) { f32x4 z = {0.f, 0.f, 0.f, 0.f}; acc[ct] = z; }
#pragma unroll
      for (int kh = 0; kh < 2; ++kh) {
        bf16x8 wB[3][6];
#pragma unroll
        for (int k2 = 0; k2 < 3; ++k2)
#pragma unroll
          for (int ct = 0; ct < 6; ++ct) {
            int col = cgB * 96 + ct * 16 + lo;
            wB[k2][ct] = ldw<WS>(p_wb, pw_f, col * 192 + (kh * 3 + k2) * 32 + hi * 8);
          }
#pragma unroll
        for (int k2 = 0; k2 < 3; ++k2) {
          bf16x8 a = *(const bf16x8*)(
              RA + swz(rtB * 16 + lo, ((kh * 3 + k2) * 4 + hi) * 16, 384));
#pragma unroll
          for (int ct = 0; ct < 6; ++ct) acc[ct] = mfma16(a, wB[k2][ct], acc[ct]);
        }
      }
      float* outp = out + (size_t)win * 12288;
#pragma unroll
      for (int ct = 0; ct < 6; ++ct) {
        int col = cgB * 96 + ct * 16 + lo;
        float bv = pb[col];
#pragma unroll
        for (int i = 0; i < 4; ++i)
          outp[(rtB * 16 + hi * 4 + i) * 192 + col] = acc[ct][i] + bv;
      }
    }
    // loop-top barrier_vm orders out-proj RA reads (lgkm-drained) before the
    // next convert overwrites RA, and completes the x2(j+1) DMA.
  }
}

extern "C" void kernel_launch(void* const* d_in, const int* in_sizes, int n_in,
                              void* d_out, int out_size, void* d_ws, size_t ws_size,
                              hipStream_t stream) {
  const float* x1 = (const float*)d_in[0];
  const float* x2 = (const float*)d_in[1];
  const float* mask = (const float*)d_in[2];
  const float* qw = (const float*)d_in[3];
  const float* qb = (const float*)d_in[4];
  const float* kvw = (const float*)d_in[5];
  const float* kvb = (const float*)d_in[6];
  const float* pw = (const float*)d_in[7];
  const float* pb = (const float*)d_in[8];
  const float* table = (const float*)d_in[9];
  float* out = (float*)d_out;
  bf16_t* wsb = (bf16_t*)d_ws;
  const int LDS_BYTES = 122880;
  if (ws_size >= 294912) {
    prep<<<144, 256, 0, stream>>>(qw, kvw, pw, wsb);
    wca_main<true><<<256, 512, LDS_BYTES, stream>>>(x1, x2, mask, qw, qb, kvw, kvb,
                                                    pw, pb, table, wsb, out);
  } else {
    wca_main<false><<<256, 512, LDS_BYTES, stream>>>(x1, x2, mask, qw, qb, kvw, kvb,
                                                     pw, pb, table, wsb, out);
  }
}

// Round 9
// 853.785 us; speedup vs baseline: 2.0951x; 2.0951x over previous
//
#include <hip/hip_runtime.h>

typedef __bf16 bf16_t;
typedef __bf16 bf16x8 __attribute__((ext_vector_type(8)));
typedef __bf16 bf16x4 __attribute__((ext_vector_type(4)));
typedef __bf16 bf16x2 __attribute__((ext_vector_type(2)));
typedef float f32x4 __attribute__((ext_vector_type(4)));

#define SCALE 0.17677669529663687f

__device__ __forceinline__ f32x4 mfma16(bf16x8 a, bf16x8 b, f32x4 c) {
  return __builtin_amdgcn_mfma_f32_16x16x32_bf16(a, b, c, 0, 0, 0);
}

// XOR-swizzled LDS byte offset: 16B-granule index XORed with (row&7).
__device__ __forceinline__ int swz(int row, int colByte, int strideB) {
  return row * strideB + ((((colByte >> 4) ^ (row & 7)) << 4) | (colByte & 15));
}

// lgkm-only barrier: orders LDS producer->consumer, leaves global loads in
// flight (no vmcnt drain). Proven r5-r7.
__device__ __forceinline__ void barrier_nd() {
  asm volatile("s_waitcnt lgkmcnt(0)" ::: "memory");
  __builtin_amdgcn_s_barrier();
  asm volatile("" ::: "memory");
}

union CvtU { bf16x2 h; unsigned int u; };
union PaU { unsigned int u[4]; bf16x8 v; };

// ws: bf16 weights. q_wb [0,36864) PRE-SCALED by SCALE, kv_wb [36864,110592),
// proj_wb [110592,147456). 294912 bytes.
__global__ void prep(const float* __restrict__ qw, const float* __restrict__ kvw,
                     const float* __restrict__ pw, bf16_t* __restrict__ wsb) {
  int i = blockIdx.x * 256 + threadIdx.x;
#pragma unroll
  for (int j = 0; j < 4; ++j) {
    int e = i * 4 + j;
    float v;
    if (e < 36864) v = qw[e] * SCALE;
    else if (e < 110592) v = kvw[e - 36864];
    else v = pw[e - 110592];
    wsb[e] = (bf16_t)v;
  }
}

template <bool WS>
__device__ __forceinline__ bf16x8 ldw(const bf16_t* __restrict__ wb,
                                      const float* __restrict__ wf, int off) {
  if constexpr (WS) {
    return *(const bf16x8*)(wb + off);
  } else {
    const float4* p = (const float4*)(wf + off);
    float4 a = p[0], c = p[1];
    bf16x8 r;
    r[0] = (bf16_t)a.x; r[1] = (bf16_t)a.y; r[2] = (bf16_t)a.z; r[3] = (bf16_t)a.w;
    r[4] = (bf16_t)c.x; r[5] = (bf16_t)c.y; r[6] = (bf16_t)c.z; r[7] = (bf16_t)c.w;
    return r;
  }
}

// One block = TWO windows, 1024 threads = 16 waves (4 waves/SIMD for latency
// coverage; r7 had only 2). LDS = 144 KB -> 1 block/CU:
//   RA @      0 : [128][384B] x2 staged -> Q -> att-out (rows wv*64+n, swz)
//   RK @  49152 : [128][384B] K (swz)
//   RV @  98304 : [2][192][128B] V^T per window (swz)
// wv = w>>3 selects the window-group (8 waves each); per-wave work is half of
// r7's, keeping acc small and weight loads per-kk (spill-safe under 128 cap).
template <bool WS>
__global__ __launch_bounds__(1024, 4) void wca_main(
    const float* __restrict__ x1, const float* __restrict__ x2,
    const float* __restrict__ mask,
    const float* __restrict__ qw_f, const float* __restrict__ qb,
    const float* __restrict__ kvw_f, const float* __restrict__ kvb,
    const float* __restrict__ pw_f, const float* __restrict__ pb,
    const float* __restrict__ table,
    const bf16_t* __restrict__ wsb,
    float* __restrict__ out) {
  extern __shared__ char smem[];
  char* RA = smem;
  char* RK = smem + 49152;
  char* RV = smem + 98304;

  const int t = threadIdx.x;
  const int w = t >> 6, l = t & 63, lo = l & 15, hi = l >> 4;
  const int wv = w >> 3, u = w & 7;
  const int win0 = 2 * blockIdx.x;

  const bf16_t* q_wb = wsb;
  const bf16_t* kv_wb = wsb + 36864;
  const bf16_t* p_wb = wsb + 110592;

  // ---------- stage x2 (both windows) -> RA ----------
  {
    const float4* s2a = (const float4*)(x2 + (size_t)win0 * 12288);
    const float4* s2b = (const float4*)(x2 + (size_t)(win0 + 1) * 12288);
#pragma unroll
    for (int it = 0; it < 3; ++it) {
      int G = it * 1024 + t;          // f32x4 granule, [0,3072)
      int n = G / 48, g = G - n * 48;
      float4 a = s2a[G];
      bf16x4 o;
      o[0] = (bf16_t)a.x; o[1] = (bf16_t)a.y; o[2] = (bf16_t)a.z; o[3] = (bf16_t)a.w;
      *(bf16x4*)(RA + swz(n, g * 8, 384)) = o;
      a = s2b[G];
      o[0] = (bf16_t)a.x; o[1] = (bf16_t)a.y; o[2] = (bf16_t)a.z; o[3] = (bf16_t)a.w;
      *(bf16x4*)(RA + swz(64 + n, g * 8, 384)) = o;
    }
  }
  barrier_nd();

  // ---------- phase A: KV proj. group wv does window wv; u: K(0-3)/V(4-7) ----------
  {
    const int part = u >> 2;            // 0 = K, 1 = V
    const int kcol = (u & 3) * 48;
    f32x4 acc[4][3];
#pragma unroll
    for (int rt = 0; rt < 4; ++rt)
#pragma unroll
      for (int ct = 0; ct < 3; ++ct) { f32x4 z = {0.f, 0.f, 0.f, 0.f}; acc[rt][ct] = z; }
#pragma unroll
    for (int kk = 0; kk < 6; ++kk) {
      bf16x8 a[4];
#pragma unroll
      for (int rt = 0; rt < 4; ++rt)
        a[rt] = *(const bf16x8*)(RA + swz(wv * 64 + rt * 16 + lo, (kk * 4 + hi) * 16, 384));
      bf16x8 bw[3];
#pragma unroll
      for (int ct = 0; ct < 3; ++ct) {
        int row = part * 192 + kcol + ct * 16 + lo;
        bw[ct] = ldw<WS>(kv_wb, kvw_f, row * 192 + kk * 32 + hi * 8);
      }
#pragma unroll
      for (int rt = 0; rt < 4; ++rt)
#pragma unroll
        for (int ct = 0; ct < 3; ++ct)
          acc[rt][ct] = mfma16(a[rt], bw[ct], acc[rt][ct]);
    }
    if (part == 0) {
#pragma unroll
      for (int ct = 0; ct < 3; ++ct) {
        int och = kcol + ct * 16 + lo;
        float bv = kvb[och];
#pragma unroll
        for (int rt = 0; rt < 4; ++rt)
#pragma unroll
          for (int i = 0; i < 4; ++i)
            *(bf16_t*)(RK + swz(wv * 64 + rt * 16 + hi * 4 + i, och * 2, 384)) =
                (bf16_t)(acc[rt][ct][i] + bv);
      }
    } else {
#pragma unroll
      for (int ct = 0; ct < 3; ++ct) {
        int och = kcol + ct * 16 + lo;
        float bv = kvb[192 + och];
#pragma unroll
        for (int rt = 0; rt < 4; ++rt) {
          int n0 = rt * 16 + hi * 4;
          bf16x4 pk;
#pragma unroll
          for (int i = 0; i < 4; ++i) pk[i] = (bf16_t)(acc[rt][ct][i] + bv);
          *(bf16x4*)(RV + wv * 24576 + swz(och, n0 * 2, 128)) = pk;
        }
      }
    }
  }
  barrier_nd();  // x2 reads done; K, V^T ready

  // ---------- phase B: Q proj from global x1 -> RA. u: rt = u&3, cg = u>>2 ----------
  {
    const int rt = u & 3, cg = u >> 2;
    const float4* p = (const float4*)(x1 + (size_t)(win0 + wv) * 12288 + (rt * 16 + lo) * 192);
    f32x4 acc[6];
#pragma unroll
    for (int ct = 0; ct < 6; ++ct) { f32x4 z = {0.f, 0.f, 0.f, 0.f}; acc[ct] = z; }
#pragma unroll
    for (int kk = 0; kk < 6; ++kk) {
      float4 xa = p[kk * 8 + hi * 2], xb = p[kk * 8 + hi * 2 + 1];
      bf16x8 wB[6];
#pragma unroll
      for (int ct = 0; ct < 6; ++ct) {
        int col = cg * 96 + ct * 16 + lo;
        wB[ct] = ldw<WS>(q_wb, qw_f, col * 192 + kk * 32 + hi * 8);
      }
      bf16x8 a;
      a[0] = (bf16_t)xa.x; a[1] = (bf16_t)xa.y; a[2] = (bf16_t)xa.z; a[3] = (bf16_t)xa.w;
      a[4] = (bf16_t)xb.x; a[5] = (bf16_t)xb.y; a[6] = (bf16_t)xb.z; a[7] = (bf16_t)xb.w;
#pragma unroll
      for (int ct = 0; ct < 6; ++ct) acc[ct] = mfma16(a, wB[ct], acc[ct]);
    }
#pragma unroll
    for (int ct = 0; ct < 6; ++ct) {
      int col = cg * 96 + ct * 16 + lo;
#pragma unroll
      for (int i = 0; i < 4; ++i) {
        float val = WS ? (acc[ct][i] + qb[col] * SCALE)
                       : (acc[ct][i] + qb[col]) * SCALE;
        *(bf16_t*)(RA + swz(wv * 64 + rt * 16 + hi * 4 + i, col * 2, 384)) = (bf16_t)val;
      }
    }
  }
  barrier_nd();  // Q ready

  // ---------- attention: wave = (wv, rt16 = u>>1, hh = u&1) ----------
  // 16 rows x 3 heads per wave. att-out overwrites Q in RA: each wave reads Q
  // only at (its 16 rows x its head-half cols) strictly before writing att-out
  // to the same tile; other waves are disjoint in rows or cols.
  {
    const int rt16 = u >> 1, hh = u & 1, rbase = rt16 * 16;
    const int r = rbase + lo;
    const int win = win0 + wv;
    const float* maskp = mask + (size_t)(win & 1023) * 4096 + r * 64;
    f32x4 mk[4];
    int ridx[4][4];
#pragma unroll
    for (int ct = 0; ct < 4; ++ct) {
      mk[ct] = *(const f32x4*)(maskp + ct * 16 + hi * 4);
#pragma unroll
      for (int i = 0; i < 4; ++i) {
        int c = ct * 16 + hi * 4 + i;
        ridx[ct][i] = (((r >> 3) - (c >> 3) + 7) * 15 + ((r & 7) - (c & 7) + 7)) * 6;
      }
    }
#pragma unroll
    for (int hq = 0; hq < 3; ++hq) {
      const int h = hh * 3 + hq;
      f32x4 cb[4];
#pragma unroll
      for (int ct = 0; ct < 4; ++ct) {
#pragma unroll
        for (int i = 0; i < 4; ++i) cb[ct][i] = table[ridx[ct][i] + h];
        cb[ct] += mk[ct];
      }
      bf16x8 qa = *(const bf16x8*)(RA + swz(wv * 64 + r, h * 64 + hi * 16, 384));
      f32x4 s[4];
#pragma unroll
      for (int ct = 0; ct < 4; ++ct) {
        bf16x8 ka = *(const bf16x8*)(RK + swz(wv * 64 + ct * 16 + lo, h * 64 + hi * 16, 384));
        s[ct] = mfma16(ka, qa, cb[ct]);  // lane holds S[r][ct*16+hi*4+i]
      }
      float mx = -1e30f;
#pragma unroll
      for (int ct = 0; ct < 4; ++ct)
#pragma unroll
        for (int i = 0; i < 4; ++i) mx = fmaxf(mx, s[ct][i]);
      mx = fmaxf(mx, __shfl_xor(mx, 16));
      mx = fmaxf(mx, __shfl_xor(mx, 32));
      float sum = 0.f;
#pragma unroll
      for (int ct = 0; ct < 4; ++ct)
#pragma unroll
        for (int i = 0; i < 4; ++i) {
          float p = __expf(s[ct][i] - mx);
          s[ct][i] = p;
          sum += p;
        }
      sum += __shfl_xor(sum, 16);
      sum += __shfl_xor(sum, 32);
      float rinv = 1.0f / sum;
      unsigned int word[4][2];
#pragma unroll
      for (int ct = 0; ct < 4; ++ct)
#pragma unroll
        for (int i2 = 0; i2 < 2; ++i2) {
          CvtU cu;
          cu.h[0] = (bf16_t)(s[ct][2 * i2] * rinv);
          cu.h[1] = (bf16_t)(s[ct][2 * i2 + 1] * rinv);
          word[ct][i2] = cu.u;
        }
      // PV: build A-frag P[rbase+lo][k-run] via shfl word-pulls
      f32x4 o0 = {0.f, 0.f, 0.f, 0.f}, o1 = {0.f, 0.f, 0.f, 0.f};
#pragma unroll
      for (int k2 = 0; k2 < 2; ++k2) {
        PaU pa;
#pragma unroll
        for (int j2 = 0; j2 < 4; ++j2) {
          int src = lo + ((hi & 1) << 5) + ((j2 >> 1) << 4);
          unsigned int wa = (unsigned int)__shfl((int)word[2 * k2][j2 & 1], src);
          unsigned int wb = (unsigned int)__shfl((int)word[2 * k2 + 1][j2 & 1], src);
          pa.u[j2] = (hi & 2) ? wb : wa;
        }
        bf16x8 v0 = *(const bf16x8*)(RV + wv * 24576 + swz(h * 32 + lo, k2 * 64 + hi * 16, 128));
        bf16x8 v1 = *(const bf16x8*)(RV + wv * 24576 + swz(h * 32 + 16 + lo, k2 * 64 + hi * 16, 128));
        o0 = mfma16(pa.v, v0, o0);
        o1 = mfma16(pa.v, v1, o1);
      }
#pragma unroll
      for (int i = 0; i < 4; ++i) {
        int rr = wv * 64 + rbase + hi * 4 + i;
        *(bf16_t*)(RA + swz(rr, h * 64 + lo * 2, 384)) = (bf16_t)o0[i];
        *(bf16_t*)(RA + swz(rr, h * 64 + 32 + lo * 2, 384)) = (bf16_t)o1[i];
      }
    }
  }
  barrier_nd();  // att-out fully in RA

  // ---------- out proj: wave = (wv, ro = u>>2, cgo = u&3) ----------
  {
    const int ro = u >> 2, cgo = u & 3;
    f32x4 acc[2][3];
#pragma unroll
    for (int rt = 0; rt < 2; ++rt)
#pragma unroll
      for (int ct = 0; ct < 3; ++ct) { f32x4 z = {0.f, 0.f, 0.f, 0.f}; acc[rt][ct] = z; }
#pragma unroll
    for (int kk = 0; kk < 6; ++kk) {
      bf16x8 a[2];
#pragma unroll
      for (int rt = 0; rt < 2; ++rt)
        a[rt] = *(const bf16x8*)(
            RA + swz(wv * 64 + ro * 32 + rt * 16 + lo, (kk * 4 + hi) * 16, 384));
      bf16x8 wO[3];
#pragma unroll
      for (int ct = 0; ct < 3; ++ct) {
        int col = cgo * 48 + ct * 16 + lo;
        wO[ct] = ldw<WS>(p_wb, pw_f, col * 192 + kk * 32 + hi * 8);
      }
#pragma unroll
      for (int rt = 0; rt < 2; ++rt)
#pragma unroll
        for (int ct = 0; ct < 3; ++ct)
          acc[rt][ct] = mfma16(a[rt], wO[ct], acc[rt][ct]);
    }
    float* outp = out + (size_t)(win0 + wv) * 12288;
#pragma unroll
    for (int ct = 0; ct < 3; ++ct) {
      int col = cgo * 48 + ct * 16 + lo;
      float bv = pb[col];
#pragma unroll
      for (int rt = 0; rt < 2; ++rt)
#pragma unroll
        for (int i = 0; i < 4; ++i)
          outp[(ro * 32 + rt * 16 + hi * 4 + i) * 192 + col] = acc[rt][ct][i] + bv;
    }
  }
}

extern "C" void kernel_launch(void* const* d_in, const int* in_sizes, int n_in,
                              void* d_out, int out_size, void* d_ws, size_t ws_size,
                              hipStream_t stream) {
  const float* x1 = (const float*)d_in[0];
  const float* x2 = (const float*)d_in[1];
  const float* mask = (const float*)d_in[2];
  const float* qw = (const float*)d_in[3];
  const float* qb = (const float*)d_in[4];
  const float* kvw = (const float*)d_in[5];
  const float* kvb = (const float*)d_in[6];
  const float* pw = (const float*)d_in[7];
  const float* pb = (const float*)d_in[8];
  const float* table = (const float*)d_in[9];
  float* out = (float*)d_out;
  bf16_t* wsb = (bf16_t*)d_ws;
  const int LDS_BYTES = 147456;
  if (ws_size >= 294912) {
    prep<<<144, 256, 0, stream>>>(qw, kvw, pw, wsb);
    wca_main<true><<<4096, 1024, LDS_BYTES, stream>>>(x1, x2, mask, qw, qb, kvw, kvb,
                                                      pw, pb, table, wsb, out);
  } else {
    wca_main<false><<<4096, 1024, LDS_BYTES, stream>>>(x1, x2, mask, qw, qb, kvw, kvb,
                                                       pw, pb, table, wsb, out);
  }
}